// Round 12
// baseline (230.992 us; speedup 1.0000x reference)
//
#include <hip/hip_runtime.h>
#include <hip/hip_cooperative_groups.h>
#include <math.h>

namespace cg = cooperative_groups;

// Problem constants (from reference)
#define NATOMS 262144
#define NGRAPH 4096
#define DIM    512
#define VOC    100
#define GPB    16          // graphs per block in accum path
#define KC     8           // K-split chunks for the S@w1 matmul
#define KLEN   (DIM / KC)  // 64
#define ROWS   104         // 103 rows padded to 104
#define HROW   104         // Hf row stride (floats)
#define NBLK   512         // cooperative grid
#define NTHR   256
#define AB     256         // accum blocks (NGRAPH/GPB)
#define MB     208         // mat blocks (13*2*KC)
#define G3     8           // graphs per block in phase 3 (NGRAPH/NBLK)

// Workspace layout (bytes):
//   Hf      f32 [NGRAPH][104]   @ 0          = 1,703,936   (mean-applied features)
//   M1      f32 [103][512]      @ 1,703,936  =   210,944
//   partial f32 [KC][104][512]  @ 1,914,880  = 1,703,936
// total 3,618,816 B (ws ~268 MB)

__device__ __forceinline__ float gelu_tanh(float x) {
    const float c = 0.7978845608028654f; // sqrt(2/pi)
    float x3 = x * x * x;
    return 0.5f * x * (1.0f + tanhf(c * (x + 0.044715f * x3)));
}

__device__ __forceinline__ int lower_bound(const int* __restrict__ a, int n, int t) {
    int lo = 0, hi = n;
    while (lo < hi) {
        int mid = (lo + hi) >> 1;
        if (a[mid] < t) lo = mid + 1; else hi = mid;
    }
    return lo;
}

// ---------------- single cooperative kernel: all three phases ----------------
__global__ void k_all(const int* __restrict__ an, const float* __restrict__ pos,
                      const int* __restrict__ batch,
                      const float* __restrict__ embed, const float* __restrict__ w_pos,
                      const float* __restrict__ w1, const float* __restrict__ b1,
                      const float* __restrict__ w2, const float* __restrict__ b2,
                      float* __restrict__ Hf, float* __restrict__ partial,
                      float* __restrict__ M1, float* __restrict__ out, int n) {
    cg::grid_group grid = cg::this_grid();
    const int b = blockIdx.x;
    const int t = threadIdx.x;           // 0..255

    __shared__ int   lh[GPB][VOC];       // phase-1 accum (6.4 KB)
    __shared__ float lps[GPB][3];
    __shared__ int   lcnt[GPB];
    __shared__ int   range[2];
    __shared__ float smat[8][KLEN];      // phase-1 mat (2 KB)
    __shared__ __align__(16) float hT[ROWS][G3];   // phase-3 (3.3 KB)
    __shared__ float part[4][G3];

    // ================= phase 1 =================
    if (b < AB) {
        // ---- accum path: block owns graphs [b*GPB,(b+1)*GPB), batch sorted ----
        const int g0 = b * GPB;

        for (int idx = t; idx < GPB * VOC; idx += NTHR) ((int*)lh)[idx] = 0;
        if (t < GPB * 3) ((float*)lps)[t] = 0.0f;
        if (t < GPB)     lcnt[t] = 0;
        if (t == 0) range[0] = lower_bound(batch, n, g0);
        if (t == 1) range[1] = lower_bound(batch, n, g0 + GPB);
        __syncthreads();

        const int lo = range[0], hi = range[1];

        for (int base = lo; base < hi; base += NTHR) {
            int i = base + t;
            bool act = (i < hi);
            int ic = act ? i : (hi - 1);     // clamped: defined g on every lane
            int g = batch[ic];
            int rel = g - g0;

            float px = 0.f, py = 0.f, pz = 0.f;
            if (act) {
                int v = an[i];
                px = pos[3 * i + 0];
                py = pos[3 * i + 1];
                pz = pos[3 * i + 2];
                atomicAdd(&lh[rel][v], 1);   // LDS atomic, spread addresses
            }

            int lane = t & 63;
            int gFirst = __shfl(g, 0);
            int gLast  = __shfl(g, 63);
            if (gFirst == gLast) {
                float sx = px, sy = py, sz = pz;
                int   sc = act ? 1 : 0;
                #pragma unroll
                for (int off = 32; off; off >>= 1) {
                    sx += __shfl_down(sx, off);
                    sy += __shfl_down(sy, off);
                    sz += __shfl_down(sz, off);
                    sc += __shfl_down(sc, off);
                }
                if (lane == 0 && sc > 0) {
                    atomicAdd(&lps[rel][0], sx);
                    atomicAdd(&lps[rel][1], sy);
                    atomicAdd(&lps[rel][2], sz);
                    atomicAdd(&lcnt[rel], sc);
                }
            } else if (act) {
                atomicAdd(&lps[rel][0], px);
                atomicAdd(&lps[rel][1], py);
                atomicAdd(&lps[rel][2], pz);
                atomicAdd(&lcnt[rel], 1);
            }
        }
        __syncthreads();

        // exclusive write-out, mean pre-applied (no atomics)
        for (int idx = t; idx < GPB * HROW; idx += NTHR) {
            int u = idx / HROW, c = idx - u * HROW;
            float inv = 1.0f / fmaxf((float)lcnt[u], 1.0f);
            float val = 0.0f;
            if (c < VOC)          val = (float)lh[u][c] * inv;
            else if (c < VOC + 3) val = lps[u][c - VOC] * inv;
            Hf[(size_t)(g0 + u) * HROW + c] = val;
        }
    } else if (b < AB + MB) {
        // ---- mat-partial path: split-K of M1 = concat(embed,w_pos) @ w1 ----
        const int mb = b - AB;
        const int kc = mb & (KC - 1);        // 0..7
        const int rc = mb >> 3;              // 0..25
        const int rt = rc >> 1;              // 0..12
        const int cc = rc & 1;               // 0..1
        const int j  = cc * 256 + t;
        const int r0 = rt * 8;
        const int k0 = kc * KLEN;

        for (int idx = t; idx < 8 * KLEN; idx += NTHR) {
            int rr = idx / KLEN, k = idx & (KLEN - 1);
            int r = r0 + rr;
            float val = 0.0f;
            if (r < VOC)          val = embed[r * DIM + k0 + k];
            else if (r < VOC + 3) val = w_pos[(r - VOC) * DIM + k0 + k];
            smat[rr][k] = val;
        }
        __syncthreads();

        float acc[8];
        #pragma unroll
        for (int rr = 0; rr < 8; rr++) acc[rr] = 0.0f;

        #pragma unroll 8
        for (int k = 0; k < KLEN; k++) {
            float w = w1[(k0 + k) * DIM + j];    // coalesced; 8 in flight
            #pragma unroll
            for (int rr = 0; rr < 8; rr++)
                acc[rr] = fmaf(smat[rr][k], w, acc[rr]);   // LDS broadcast
        }

        #pragma unroll
        for (int rr = 0; rr < 8; rr++)
            partial[((size_t)kc * ROWS + r0 + rr) * DIM + j] = acc[rr];
    }
    // idle blocks [AB+MB, NBLK) fall through

    grid.sync();   // Hf + partial globally visible

    // ================= phase 2 (+ phase-3 LDS staging overlap) =================
    {
        const int G0 = b * G3;
        // stage hT[v][u] for this block's 8 graphs (needs only Hf)
        for (int idx = t; idx < G3 * HROW; idx += NTHR) {
            int u = idx / HROW;                // 0..7
            int v = idx - u * HROW;            // 0..103 (coalesced global read)
            hT[v][u] = Hf[(size_t)(G0 + u) * HROW + v];
        }
        // reduce partials -> M1 (first 206 blocks' threads)
        int idx = b * NTHR + t;
        if (idx < 103 * DIM) {
            int r = idx / DIM, j = idx - r * DIM;
            float sum = 0.0f;
            #pragma unroll
            for (int kc = 0; kc < KC; kc++)
                sum += partial[((size_t)kc * ROWS + r) * DIM + j];
            M1[r * DIM + j] = sum;
        }
    }

    grid.sync();   // M1 globally visible (hT covered by the barrier too)

    // ================= phase 3: Hf@M1 + gelu + dot(w2) =================
    {
        const int G0 = b * G3;
        float acc0[G3], acc1[G3];
        #pragma unroll
        for (int u = 0; u < G3; u++) { acc0[u] = 0.0f; acc1[u] = 0.0f; }

        for (int v = 0; v < VOC + 3; v++) {
            float m0 = M1[v * DIM + t];          // coalesced, L2-resident
            float m1 = M1[v * DIM + t + 256];
            const float4* hp = (const float4*)(&hT[v][0]);
            float4 ha = hp[0], hb = hp[1];       // broadcast b128
            acc0[0] = fmaf(ha.x, m0, acc0[0]);  acc1[0] = fmaf(ha.x, m1, acc1[0]);
            acc0[1] = fmaf(ha.y, m0, acc0[1]);  acc1[1] = fmaf(ha.y, m1, acc1[1]);
            acc0[2] = fmaf(ha.z, m0, acc0[2]);  acc1[2] = fmaf(ha.z, m1, acc1[2]);
            acc0[3] = fmaf(ha.w, m0, acc0[3]);  acc1[3] = fmaf(ha.w, m1, acc1[3]);
            acc0[4] = fmaf(hb.x, m0, acc0[4]);  acc1[4] = fmaf(hb.x, m1, acc1[4]);
            acc0[5] = fmaf(hb.y, m0, acc0[5]);  acc1[5] = fmaf(hb.y, m1, acc1[5]);
            acc0[6] = fmaf(hb.z, m0, acc0[6]);  acc1[6] = fmaf(hb.z, m1, acc1[6]);
            acc0[7] = fmaf(hb.w, m0, acc0[7]);  acc1[7] = fmaf(hb.w, m1, acc1[7]);
        }

        float bj0 = b1[t],       bj1 = b1[t + 256];
        float wj0 = w2[t],       wj1 = w2[t + 256];
        float con[G3];
        #pragma unroll
        for (int u = 0; u < G3; u++)
            con[u] = gelu_tanh(acc0[u] + bj0) * wj0 + gelu_tanh(acc1[u] + bj1) * wj1;

        int wave = t >> 6;
        int lane = t & 63;
        #pragma unroll
        for (int u = 0; u < G3; u++) {
            float s = con[u];
            #pragma unroll
            for (int off = 32; off; off >>= 1) s += __shfl_down(s, off);
            if (lane == 0) part[wave][u] = s;
        }
        __syncthreads();

        if (t < G3)
            out[G0 + t] = part[0][t] + part[1][t] + part[2][t] + part[3][t] + b2[0];
    }
}

// ---------------- 3-kernel fallback (measured-correct R11 path) ----------------
__global__ void k_fused(const int* __restrict__ an, const float* __restrict__ pos,
                        const int* __restrict__ batch,
                        const float* __restrict__ embed, const float* __restrict__ w_pos,
                        const float* __restrict__ w1,
                        float* __restrict__ Hf, float* __restrict__ partial, int n) {
    const int t = threadIdx.x;

    if (blockIdx.x < AB) {
        const int g0 = blockIdx.x * GPB;
        __shared__ int   lh[GPB][VOC];
        __shared__ float lps[GPB][3];
        __shared__ int   lcnt[GPB];
        __shared__ int   range[2];

        for (int idx = t; idx < GPB * VOC; idx += 256) ((int*)lh)[idx] = 0;
        if (t < GPB * 3) ((float*)lps)[t] = 0.0f;
        if (t < GPB)     lcnt[t] = 0;
        if (t == 0) range[0] = lower_bound(batch, n, g0);
        if (t == 1) range[1] = lower_bound(batch, n, g0 + GPB);
        __syncthreads();

        const int lo = range[0], hi = range[1];
        for (int base = lo; base < hi; base += 256) {
            int i = base + t;
            bool act = (i < hi);
            int ic = act ? i : (hi - 1);
            int g = batch[ic];
            int rel = g - g0;
            float px = 0.f, py = 0.f, pz = 0.f;
            if (act) {
                int v = an[i];
                px = pos[3 * i]; py = pos[3 * i + 1]; pz = pos[3 * i + 2];
                atomicAdd(&lh[rel][v], 1);
            }
            int lane = t & 63;
            int gFirst = __shfl(g, 0);
            int gLast  = __shfl(g, 63);
            if (gFirst == gLast) {
                float sx = px, sy = py, sz = pz;
                int sc = act ? 1 : 0;
                #pragma unroll
                for (int off = 32; off; off >>= 1) {
                    sx += __shfl_down(sx, off); sy += __shfl_down(sy, off);
                    sz += __shfl_down(sz, off); sc += __shfl_down(sc, off);
                }
                if (lane == 0 && sc > 0) {
                    atomicAdd(&lps[rel][0], sx); atomicAdd(&lps[rel][1], sy);
                    atomicAdd(&lps[rel][2], sz); atomicAdd(&lcnt[rel], sc);
                }
            } else if (act) {
                atomicAdd(&lps[rel][0], px); atomicAdd(&lps[rel][1], py);
                atomicAdd(&lps[rel][2], pz); atomicAdd(&lcnt[rel], 1);
            }
        }
        __syncthreads();

        for (int idx = t; idx < GPB * HROW; idx += 256) {
            int u = idx / HROW, c = idx - u * HROW;
            float inv = 1.0f / fmaxf((float)lcnt[u], 1.0f);
            float val = 0.0f;
            if (c < VOC)          val = (float)lh[u][c] * inv;
            else if (c < VOC + 3) val = lps[u][c - VOC] * inv;
            Hf[(size_t)(g0 + u) * HROW + c] = val;
        }
    } else {
        const int mb = blockIdx.x - AB;
        const int kc = mb & (KC - 1);
        const int rc = mb >> 3;
        const int rt = rc >> 1;
        const int cc = rc & 1;
        const int j  = cc * 256 + t;
        const int r0 = rt * 8;
        const int k0 = kc * KLEN;

        __shared__ float s[8][KLEN];
        for (int idx = t; idx < 8 * KLEN; idx += 256) {
            int rr = idx / KLEN, k = idx & (KLEN - 1);
            int r = r0 + rr;
            float val = 0.0f;
            if (r < VOC)          val = embed[r * DIM + k0 + k];
            else if (r < VOC + 3) val = w_pos[(r - VOC) * DIM + k0 + k];
            s[rr][k] = val;
        }
        __syncthreads();

        float acc[8];
        #pragma unroll
        for (int rr = 0; rr < 8; rr++) acc[rr] = 0.0f;
        #pragma unroll 8
        for (int k = 0; k < KLEN; k++) {
            float w = w1[(k0 + k) * DIM + j];
            #pragma unroll
            for (int rr = 0; rr < 8; rr++)
                acc[rr] = fmaf(s[rr][k], w, acc[rr]);
        }
        #pragma unroll
        for (int rr = 0; rr < 8; rr++)
            partial[((size_t)kc * ROWS + r0 + rr) * DIM + j] = acc[rr];
    }
}

__global__ void k_reduce(const float* __restrict__ partial, float* __restrict__ M1) {
    int idx = blockIdx.x * 256 + threadIdx.x;
    if (idx >= 103 * DIM) return;
    int r = idx / DIM, j = idx - r * DIM;
    float sum = 0.0f;
    #pragma unroll
    for (int kc = 0; kc < KC; kc++)
        sum += partial[((size_t)kc * ROWS + r) * DIM + j];
    M1[r * DIM + j] = sum;
}

__global__ void k_final(const float* __restrict__ Hf, const float* __restrict__ M1,
                        const float* __restrict__ b1, const float* __restrict__ w2,
                        const float* __restrict__ b2, float* __restrict__ out) {
    const int G0 = blockIdx.x * 16;
    const int j = threadIdx.x;

    __shared__ __align__(16) float hT[HROW][20];
    __shared__ float part[8][16];

    for (int idx = j; idx < 16 * HROW; idx += 512) {
        int u = idx / HROW;
        int v = idx - u * HROW;
        hT[v][u] = Hf[(size_t)(G0 + u) * HROW + v];
    }
    __syncthreads();

    float acc[16];
    #pragma unroll
    for (int u = 0; u < 16; u++) acc[u] = 0.0f;

    for (int v = 0; v < VOC + 3; v++) {
        float m = M1[v * DIM + j];
        const float4* hp = (const float4*)(&hT[v][0]);
        float4 h0 = hp[0], h1 = hp[1], h2 = hp[2], h3 = hp[3];
        acc[ 0] = fmaf(h0.x, m, acc[ 0]); acc[ 1] = fmaf(h0.y, m, acc[ 1]);
        acc[ 2] = fmaf(h0.z, m, acc[ 2]); acc[ 3] = fmaf(h0.w, m, acc[ 3]);
        acc[ 4] = fmaf(h1.x, m, acc[ 4]); acc[ 5] = fmaf(h1.y, m, acc[ 5]);
        acc[ 6] = fmaf(h1.z, m, acc[ 6]); acc[ 7] = fmaf(h1.w, m, acc[ 7]);
        acc[ 8] = fmaf(h2.x, m, acc[ 8]); acc[ 9] = fmaf(h2.y, m, acc[ 9]);
        acc[10] = fmaf(h2.z, m, acc[10]); acc[11] = fmaf(h2.w, m, acc[11]);
        acc[12] = fmaf(h3.x, m, acc[12]); acc[13] = fmaf(h3.y, m, acc[13]);
        acc[14] = fmaf(h3.z, m, acc[14]); acc[15] = fmaf(h3.w, m, acc[15]);
    }

    float bj = b1[j];
    float wj = w2[j];
    float contrib[16];
    #pragma unroll
    for (int u = 0; u < 16; u++)
        contrib[u] = gelu_tanh(acc[u] + bj) * wj;

    int wave = j >> 6;
    int lane = j & 63;
    #pragma unroll
    for (int u = 0; u < 16; u++) {
        float s = contrib[u];
        #pragma unroll
        for (int off = 32; off; off >>= 1) s += __shfl_down(s, off);
        if (lane == 0) part[wave][u] = s;
    }
    __syncthreads();

    if (j < 16) {
        float e = 0.0f;
        #pragma unroll
        for (int w = 0; w < 8; w++) e += part[w][j];
        out[G0 + j] = e + b2[0];
    }
}

extern "C" void kernel_launch(void* const* d_in, const int* in_sizes, int n_in,
                              void* d_out, int out_size, void* d_ws, size_t ws_size,
                              hipStream_t stream) {
    const int*   an    = (const int*)d_in[0];
    const float* pos   = (const float*)d_in[1];
    const int*   batch = (const int*)d_in[2];
    const float* embed = (const float*)d_in[3];
    const float* w_pos = (const float*)d_in[4];
    const float* w1    = (const float*)d_in[5];
    const float* b1    = (const float*)d_in[6];
    const float* w2    = (const float*)d_in[7];
    const float* b2    = (const float*)d_in[8];
    float* out = (float*)d_out;

    int n = in_sizes[0];             // 262144

    char* ws = (char*)d_ws;
    const size_t HF_B = (size_t)NGRAPH * HROW * 4;           // 1,703,936
    const size_t M1_B = (size_t)103 * DIM * 4;               //   210,944
    float* Hf      = (float*)ws;
    float* M1      = (float*)(ws + HF_B);
    float* partial = (float*)(ws + HF_B + M1_B);

    // single cooperative dispatch: accum+mat -> reduce -> final
    void* args[] = {(void*)&an, (void*)&pos, (void*)&batch, (void*)&embed,
                    (void*)&w_pos, (void*)&w1, (void*)&b1, (void*)&w2, (void*)&b2,
                    (void*)&Hf, (void*)&partial, (void*)&M1, (void*)&out, (void*)&n};
    hipError_t err = hipLaunchCooperativeKernel((const void*)k_all, dim3(NBLK),
                                                dim3(NTHR), args, 0, stream);
    if (err != hipSuccess) {
        // fallback: measured-correct 3-kernel path (R11)
        k_fused<<<AB + MB, 256, 0, stream>>>(an, pos, batch, embed, w_pos, w1,
                                             Hf, partial, n);
        k_reduce<<<(103 * DIM + 255) / 256, 256, 0, stream>>>(partial, M1);
        k_final<<<NGRAPH / 16, 512, 0, stream>>>(Hf, M1, b1, w2, b2, out);
    }
}

// Round 13
// 120.725 us; speedup vs baseline: 1.9134x; 1.9134x over previous
//
#include <hip/hip_runtime.h>
#include <math.h>

// Problem constants (from reference)
#define NATOMS 262144
#define NGRAPH 4096
#define DIM    512
#define VOC    100
#define GPB    16          // graphs per block in accum path
#define HROW   104         // Hf row stride (floats)
#define AB     256         // accum blocks (NGRAPH/GPB)
#define MBLK   208         // mat blocks: 13 row-tiles x 16 col-chunks

// Workspace layout (bytes):
//   Hf  f32 [NGRAPH][104] @ 0          = 1,703,936   (mean-applied features)
//   M1  f32 [103][512]    @ 1,703,936  =   210,944
// total 1,914,880 B

__device__ __forceinline__ float gelu_tanh(float x) {
    const float c = 0.7978845608028654f; // sqrt(2/pi)
    float x3 = x * x * x;
    return 0.5f * x * (1.0f + tanhf(c * (x + 0.044715f * x3)));
}

__device__ __forceinline__ int lower_bound(const int* __restrict__ a, int n, int t) {
    int lo = 0, hi = n;
    while (lo < hi) {
        int mid = (lo + hi) >> 1;
        if (a[mid] < t) lo = mid + 1; else hi = mid;
    }
    return lo;
}

struct AccumS {
    int   lh[GPB][VOC];
    float lps[GPB][3];
    int   lcnt[GPB];
    int   range[2];
};
struct MatS {
    float smat[8][DIM];    // 16 KB; reused as red[8s][8r][32c] after the FMA loop
};

// Fused: blocks [0,256) = ownership-based accum -> Hf (mean pre-applied,
// zero global atomics). Blocks [256,464) = M1 = concat(embed,w_pos) @ w1,
// K split WITHIN the block (8 k-slices x 64) + LDS reduce -> M1 direct.
// No global partials, no separate reduce dispatch.
__global__ void k_fused(const int* __restrict__ an, const float* __restrict__ pos,
                        const int* __restrict__ batch,
                        const float* __restrict__ embed, const float* __restrict__ w_pos,
                        const float* __restrict__ w1,
                        float* __restrict__ Hf, float* __restrict__ M1, int n) {
    const int t = threadIdx.x;           // 0..255
    __shared__ union { AccumS a; MatS m; } sm;

    if (blockIdx.x < AB) {
        // ---------------- accum path (measured-correct R11 code) ----------------
        const int g0 = blockIdx.x * GPB;

        for (int idx = t; idx < GPB * VOC; idx += 256) ((int*)sm.a.lh)[idx] = 0;
        if (t < GPB * 3) ((float*)sm.a.lps)[t] = 0.0f;
        if (t < GPB)     sm.a.lcnt[t] = 0;
        if (t == 0) sm.a.range[0] = lower_bound(batch, n, g0);
        if (t == 1) sm.a.range[1] = lower_bound(batch, n, g0 + GPB);
        __syncthreads();

        const int lo = sm.a.range[0], hi = sm.a.range[1];

        for (int base = lo; base < hi; base += 256) {
            int i = base + t;
            bool act = (i < hi);
            int ic = act ? i : (hi - 1);     // clamped: defined g on every lane
            int g = batch[ic];
            int rel = g - g0;

            float px = 0.f, py = 0.f, pz = 0.f;
            if (act) {
                int v = an[i];
                px = pos[3 * i + 0];
                py = pos[3 * i + 1];
                pz = pos[3 * i + 2];
                atomicAdd(&sm.a.lh[rel][v], 1);   // LDS atomic, spread addresses
            }

            int lane = t & 63;
            int gFirst = __shfl(g, 0);
            int gLast  = __shfl(g, 63);
            if (gFirst == gLast) {
                float sx = px, sy = py, sz = pz;
                int   sc = act ? 1 : 0;
                #pragma unroll
                for (int off = 32; off; off >>= 1) {
                    sx += __shfl_down(sx, off);
                    sy += __shfl_down(sy, off);
                    sz += __shfl_down(sz, off);
                    sc += __shfl_down(sc, off);
                }
                if (lane == 0 && sc > 0) {
                    atomicAdd(&sm.a.lps[rel][0], sx);
                    atomicAdd(&sm.a.lps[rel][1], sy);
                    atomicAdd(&sm.a.lps[rel][2], sz);
                    atomicAdd(&sm.a.lcnt[rel], sc);
                }
            } else if (act) {
                atomicAdd(&sm.a.lps[rel][0], px);
                atomicAdd(&sm.a.lps[rel][1], py);
                atomicAdd(&sm.a.lps[rel][2], pz);
                atomicAdd(&sm.a.lcnt[rel], 1);
            }
        }
        __syncthreads();

        // exclusive write-out, mean pre-applied (no atomics)
        for (int idx = t; idx < GPB * HROW; idx += 256) {
            int u = idx / HROW, c = idx - u * HROW;
            float inv = 1.0f / fmaxf((float)sm.a.lcnt[u], 1.0f);
            float val = 0.0f;
            if (c < VOC)          val = (float)sm.a.lh[u][c] * inv;
            else if (c < VOC + 3) val = sm.a.lps[u][c - VOC] * inv;
            Hf[(size_t)(g0 + u) * HROW + c] = val;
        }
    } else {
        // ---------------- mat path: in-block split-K, direct M1 ----------------
        const int mb = blockIdx.x - AB;      // 0..207
        const int rt = mb / 16;              // 0..12  (row tile of 8)
        const int cc = mb - rt * 16;         // 0..15  (col chunk of 32)
        const int r0 = rt * 8;
        const int c  = t & 31;               // col within chunk
        const int s  = t >> 5;               // k-slice 0..7
        const int j  = cc * 32 + c;
        const int k0 = s * 64;

        // stage 8 source rows x 512 k (16 KB), coalesced
        for (int idx = t; idx < 8 * DIM; idx += 256) {
            int rr = idx >> 9;               // /512
            int k  = idx & (DIM - 1);
            int r  = r0 + rr;
            float val = 0.0f;
            if (r < VOC)          val = embed[r * DIM + k];
            else if (r < VOC + 3) val = w_pos[(r - VOC) * DIM + k];
            sm.m.smat[rr][k] = val;
        }
        __syncthreads();

        float acc[8];
        #pragma unroll
        for (int rr = 0; rr < 8; rr++) acc[rr] = 0.0f;

        #pragma unroll 8
        for (int k = 0; k < 64; k++) {
            float w = w1[(k0 + k) * DIM + j];        // 2x128B segments per wave
            #pragma unroll
            for (int rr = 0; rr < 8; rr++)
                acc[rr] = fmaf(sm.m.smat[rr][k0 + k], w, acc[rr]);  // LDS broadcast
        }
        __syncthreads();

        // in-block k-slice reduction via LDS (reuse smat)
        float* red = &sm.m.smat[0][0];               // [8s][8r][32c]
        #pragma unroll
        for (int rr = 0; rr < 8; rr++)
            red[(s * 8 + rr) * 32 + c] = acc[rr];    // consecutive banks, no conflict
        __syncthreads();

        {
            int r = t >> 5;                          // 0..7
            float sum = 0.0f;
            #pragma unroll
            for (int ss = 0; ss < 8; ss++)
                sum += red[(ss * 8 + r) * 32 + (t & 31)];
            int row = r0 + r;
            if (row < VOC + 3)
                M1[row * DIM + cc * 32 + (t & 31)] = sum;
        }
    }
}

// Final: per graph g: pre[j] = Hf[g]·M1[:,j] + b1[j];
// energy[g] = sum_j gelu(pre[j]) * w2[j] + b2.  (measured-correct R11 code)
__global__ void k_final(const float* __restrict__ Hf, const float* __restrict__ M1,
                        const float* __restrict__ b1, const float* __restrict__ w2,
                        const float* __restrict__ b2, float* __restrict__ out) {
    const int G0 = blockIdx.x * 16;
    const int j = threadIdx.x;                 // 0..511

    __shared__ __align__(16) float hT[HROW][20];   // [v][u], 80B rows
    __shared__ float part[8][16];

    for (int idx = j; idx < 16 * HROW; idx += 512) {
        int u = idx / HROW;
        int v = idx - u * HROW;
        hT[v][u] = Hf[(size_t)(G0 + u) * HROW + v];
    }
    __syncthreads();

    float acc[16];
    #pragma unroll
    for (int u = 0; u < 16; u++) acc[u] = 0.0f;

    for (int v = 0; v < VOC + 3; v++) {
        float m = M1[v * DIM + j];             // coalesced, L2-resident
        const float4* hp = (const float4*)(&hT[v][0]);
        float4 h0 = hp[0], h1 = hp[1], h2 = hp[2], h3 = hp[3];  // broadcast b128
        acc[ 0] = fmaf(h0.x, m, acc[ 0]); acc[ 1] = fmaf(h0.y, m, acc[ 1]);
        acc[ 2] = fmaf(h0.z, m, acc[ 2]); acc[ 3] = fmaf(h0.w, m, acc[ 3]);
        acc[ 4] = fmaf(h1.x, m, acc[ 4]); acc[ 5] = fmaf(h1.y, m, acc[ 5]);
        acc[ 6] = fmaf(h1.z, m, acc[ 6]); acc[ 7] = fmaf(h1.w, m, acc[ 7]);
        acc[ 8] = fmaf(h2.x, m, acc[ 8]); acc[ 9] = fmaf(h2.y, m, acc[ 9]);
        acc[10] = fmaf(h2.z, m, acc[10]); acc[11] = fmaf(h2.w, m, acc[11]);
        acc[12] = fmaf(h3.x, m, acc[12]); acc[13] = fmaf(h3.y, m, acc[13]);
        acc[14] = fmaf(h3.z, m, acc[14]); acc[15] = fmaf(h3.w, m, acc[15]);
    }

    float bj = b1[j];
    float wj = w2[j];
    float contrib[16];
    #pragma unroll
    for (int u = 0; u < 16; u++)
        contrib[u] = gelu_tanh(acc[u] + bj) * wj;

    int wave = j >> 6;
    int lane = j & 63;
    #pragma unroll
    for (int u = 0; u < 16; u++) {
        float s = contrib[u];
        #pragma unroll
        for (int off = 32; off; off >>= 1) s += __shfl_down(s, off);
        if (lane == 0) part[wave][u] = s;
    }
    __syncthreads();

    if (j < 16) {
        float e = 0.0f;
        #pragma unroll
        for (int w = 0; w < 8; w++) e += part[w][j];
        out[G0 + j] = e + b2[0];
    }
}

extern "C" void kernel_launch(void* const* d_in, const int* in_sizes, int n_in,
                              void* d_out, int out_size, void* d_ws, size_t ws_size,
                              hipStream_t stream) {
    const int*   an    = (const int*)d_in[0];
    const float* pos   = (const float*)d_in[1];
    const int*   batch = (const int*)d_in[2];
    const float* embed = (const float*)d_in[3];
    const float* w_pos = (const float*)d_in[4];
    const float* w1    = (const float*)d_in[5];
    const float* b1    = (const float*)d_in[6];
    const float* w2    = (const float*)d_in[7];
    const float* b2    = (const float*)d_in[8];
    float* out = (float*)d_out;

    const int n = in_sizes[0];       // 262144

    char* ws = (char*)d_ws;
    const size_t HF_B = (size_t)NGRAPH * HROW * 4;           // 1,703,936
    float* Hf = (float*)ws;
    float* M1 = (float*)(ws + HF_B);

    // 1) fused accum (mean-applied Hf) + full-K mat with in-block reduce -> M1
    k_fused<<<AB + MBLK, 256, 0, stream>>>(an, pos, batch, embed, w_pos, w1,
                                           Hf, M1, n);

    // 2) fused mean-matmul + gelu + final dot
    k_final<<<NGRAPH / 16, 512, 0, stream>>>(Hf, M1, b1, w2, b2, out);
}